// Round 7
// baseline (304.617 us; speedup 1.0000x reference)
//
#include <hip/hip_runtime.h>
#include <hip/hip_bf16.h>

#define EMBED 768
#define HEADS 12
#define HD 64
#define BATCH 4
#define SEQ 2048
#define M_TOK (BATCH*SEQ)   // 8192
#define N_QKV (3*EMBED)     // 2304
#define SL2E 0.18033688011112042f   // (1/8) * log2(e)

typedef short bf8 __attribute__((ext_vector_type(8)));
typedef float f4  __attribute__((ext_vector_type(4)));
typedef float f16v __attribute__((ext_vector_type(16)));
typedef unsigned short us8 __attribute__((ext_vector_type(8)));

static __device__ inline unsigned short f2bf(float f) {
    unsigned int x = __float_as_uint(f);
    unsigned int r = (x + 0x7fffu + ((x >> 16) & 1u)) >> 16;   // RNE
    return (unsigned short)r;
}

// pack two fp32 -> packed bf16x2
static __device__ inline unsigned int pack2bf(float a, float b) {
#if defined(__has_builtin)
#if __has_builtin(__builtin_amdgcn_cvt_pk_bf16_f32)
    auto r = __builtin_amdgcn_cvt_pk_bf16_f32(a, b);
    return __builtin_bit_cast(unsigned int, r);
#else
    unsigned int ua = (__float_as_uint(a) + 0x8000u) >> 16;
    unsigned int ub = (__float_as_uint(b) + 0x8000u) & 0xffff0000u;
    return ua | ub;
#endif
#else
    unsigned int ua = (__float_as_uint(a) + 0x8000u) >> 16;
    unsigned int ub = (__float_as_uint(b) + 0x8000u) & 0xffff0000u;
    return ua | ub;
#endif
}

#define GLD_LDS(gp, lp) __builtin_amdgcn_global_load_lds( \
    (const __attribute__((address_space(1))) void*)(gp),  \
    (__attribute__((address_space(3))) void*)(lp), 16, 0, 0)

// ---------------- fp32 -> bf16 elementwise ----------------
__global__ void cvt_f32_bf16(const float* __restrict__ in,
                             unsigned short* __restrict__ out, int n) {
    int i = (blockIdx.x * blockDim.x + threadIdx.x) * 4;
    if (i < n) {
        float4 v = *reinterpret_cast<const float4*>(in + i);
        ushort4 o;
        o.x = f2bf(v.x); o.y = f2bf(v.y); o.z = f2bf(v.z); o.w = f2bf(v.w);
        *reinterpret_cast<ushort4*>(out + i) = o;
    }
}

// ------- fp32 [R][C] -> bf16 [C][R] transpose; rows<nlim scaled by `scale` -------
__global__ void transpose_f32_bf16(const float* __restrict__ in,
                                   unsigned short* __restrict__ out, int R, int C,
                                   float scale, int nlim) {
    __shared__ float tile[32][33];
    int c0 = blockIdx.x * 32, r0 = blockIdx.y * 32;
    int tx = threadIdx.x, ty = threadIdx.y;      // 32 x 8
    for (int i = 0; i < 32; i += 8)
        tile[ty + i][tx] = in[(size_t)(r0 + ty + i) * C + c0 + tx];
    __syncthreads();
    for (int i = 0; i < 32; i += 8) {
        int orow = c0 + ty + i;
        float s = (orow < nlim) ? scale : 1.0f;
        out[(size_t)orow * R + r0 + tx] = f2bf(tile[tx][ty + i] * s);
    }
}

// ---------------- bias prep: scale first 768 entries by SL2E ----------------
__global__ void scale_bias(const float* __restrict__ in, float* __restrict__ out) {
    int i = blockIdx.x * 256 + threadIdx.x;
    if (i < N_QKV) out[i] = in[i] * (i < 768 ? SL2E : 1.0f);
}

// ---------------- bf16 GEMM: C[M][N] = A[M][K] * BT[N][K]^T + bias ----------------
// m97-pattern staging (unchanged from round 4). Epilogue identical to the proven
// round-1 code — round-2's branchy epilogue demoted acc to scratch (VGPR 28).
template<int OUT_MODE>  // 0: bf16 out, 1: fp32 out
__global__ __launch_bounds__(256) void gemm_bf16(
    const unsigned short* __restrict__ A,
    const unsigned short* __restrict__ BT,
    const float* __restrict__ bias,
    void* __restrict__ Cout, int M, int N, int K)
{
    const int LDA = 32;  // unpadded: lane-linear global_load_lds dest
    __shared__ unsigned short a_lds[128 * 32];
    __shared__ unsigned short b_lds[128 * 32];
    int tid  = threadIdx.x;
    int lane = tid & 63, w = tid >> 6;
    int quad = lane >> 4, cc = lane & 15;
    int m0 = blockIdx.x * 128, n0 = blockIdx.y * 128;
    int wr = w >> 1, wc = w & 1;
    int mb = wr * 64, nb = wc * 64;
    const unsigned short* Ab = A + (size_t)m0 * K;
    const unsigned short* Bb = BT + (size_t)n0 * K;
    f4 acc[4][4] = {};
    for (int k0 = 0; k0 < K; k0 += 32) {
        __syncthreads();
        for (int p = 0; p < 2; ++p) {
            int li  = p * 256 + tid;          // 0..511
            int row = li >> 2, ch = li & 3;   // 128 rows x 4 chunks of 8 halfwords
            GLD_LDS(Ab + (size_t)row * K + k0 + ch * 8, &a_lds[li * 8]);
            GLD_LDS(Bb + (size_t)row * K + k0 + ch * 8, &b_lds[li * 8]);
        }
        __syncthreads();   // vmcnt(0) drain
        bf8 af[4], bfv[4];
        for (int mi = 0; mi < 4; ++mi)
            af[mi] = *reinterpret_cast<const bf8*>(&a_lds[(mb + mi * 16 + cc) * LDA + quad * 8]);
        for (int ni = 0; ni < 4; ++ni)
            bfv[ni] = *reinterpret_cast<const bf8*>(&b_lds[(nb + ni * 16 + cc) * LDA + quad * 8]);
        for (int mi = 0; mi < 4; ++mi)
            for (int ni = 0; ni < 4; ++ni)
                acc[mi][ni] = __builtin_amdgcn_mfma_f32_16x16x32_bf16(af[mi], bfv[ni], acc[mi][ni], 0, 0, 0);
    }
    for (int mi = 0; mi < 4; ++mi)
        for (int ni = 0; ni < 4; ++ni) {
            int gn = n0 + nb + ni * 16 + cc;
            float bv = bias[gn];
            for (int r = 0; r < 4; ++r) {
                int gm = m0 + mb + mi * 16 + quad * 4 + r;
                float v = acc[mi][ni][r] + bv;
                if (OUT_MODE == 0)
                    ((unsigned short*)Cout)[(size_t)gm * N + gn] = f2bf(v);
                else
                    ((float*)Cout)[(size_t)gm * N + gn] = v;
            }
        }
}

// ------- V transpose: qkv[.][1536+h*64+d] -> vt[b][h][d][t], LDS-tiled -------
__global__ __launch_bounds__(256) void vtrans(
    const unsigned short* __restrict__ qkv, unsigned short* __restrict__ vt)
{
    __shared__ unsigned short lds[64 * 72];
    int tid = threadIdx.x;
    int t0 = blockIdx.x * 64, h = blockIdx.y, b = blockIdx.z;
    for (int p = 0; p < 2; ++p) {
        int li = p * 256 + tid, row = li >> 3, col = li & 7;
        *reinterpret_cast<uint4*>(&lds[row * 72 + col * 8]) =
            *reinterpret_cast<const uint4*>(
                qkv + (size_t)(b * SEQ + t0 + row) * 2304 + 1536 + h * 64 + col * 8);
    }
    __syncthreads();
    for (int p = 0; p < 2; ++p) {
        int li = p * 256 + tid, d = li >> 3, tc = li & 7;
        us8 v;
        for (int j = 0; j < 8; ++j) v[j] = lds[(tc * 8 + j) * 72 + d];
        *reinterpret_cast<us8*>(
            vt + ((size_t)(b * HEADS + h) * 64 + d) * SEQ + t0 + tc * 8) = v;
    }
}

// ---------------- flash attention, 32x32x16 MFMA, q x key wave split ----------------
// Round-6 post-mortem: LDS-pipe-bound (~2100 LDS-cyc/block-iter + 27% conflicts).
// New shape: 8 waves; wave w owns (q-quarter qq=w>>1: 32 rows) x (key-half kh=w&1:
// 32 of the 64-key tile). 32x32x16 MFMA amortizes each b128 fragment read over a
// 32-wide tile edge: per block-iter 80 b128 reads + 32 b64 + 16 b128 writes
// (~1344 LDS-cyc, was ~2112). P region is wave-private (own q-rows x own key-half)
// -> still no mid-loop barrier. O/lsum of the two key-halves combined once at the
// end via LDS reuse. C/D layout (m74/m101): col=lane&31, row=(reg&3)+8*(reg>>2)+4*(lane>>5).
__global__ __launch_bounds__(512, 6) void attn_kernel(
    const unsigned short* __restrict__ qkv,  // [B*T][2304] bf16 (q pre-scaled)
    const unsigned short* __restrict__ vt,   // [B][H][64][T] bf16
    unsigned short* __restrict__ out)        // [B*T][768] bf16
{
    const int LDK = 72;  // 64 + 8 pad
    __shared__ unsigned short smem[18432];   // 36864 B total
    unsigned short* k_lds = smem;            // [64][72]
    unsigned short* v_lds = smem + 4608;     // [64][72]
    unsigned short* p_lds = smem + 9216;     // [128][72]
    int tid  = threadIdx.x;
    int lane = tid & 63, w = tid >> 6;       // w = 0..7
    int ln   = lane & 31, hk = lane >> 5;    // n-index / k-half within frag
    int qq   = w >> 1, kh = w & 1;           // q-quarter, key-half
    // swizzle: all 16 q-tiles of one (b,h) share id%8 -> same XCD L2
    int id  = blockIdx.x;
    int sub = id >> 3, rem = id & 7;
    int g   = (sub >> 4) * 8 + rem;          // 0..47
    int qt  = sub & 15;
    int b   = g / HEADS, h = g % HEADS;
    int q0  = qt * 128;

    // Q resident as 32x32 B-fragments: B[n=ln -> q][k=kb*16+hk*8+j]
    bf8 qf[4];
    {
        const unsigned short* qp =
            qkv + (size_t)(b * SEQ + q0 + qq * 32 + ln) * 2304 + h * 64 + hk * 8;
        qf[0] = *reinterpret_cast<const bf8*>(qp);
        qf[1] = *reinterpret_cast<const bf8*>(qp + 16);
        qf[2] = *reinterpret_cast<const bf8*>(qp + 32);
        qf[3] = *reinterpret_cast<const bf8*>(qp + 48);
    }
    f16v acc[2] = {};            // [db=d/32]; C: col d = db*32+ln, row q = (reg&3)+8*(reg>>2)+4*hk
    float lsum = 0.f;
    const unsigned short* kbase = qkv + (size_t)b * SEQ * 2304 + 768 + h * 64;
    const unsigned short* vbase = vt + (size_t)(b * HEADS + h) * 64 * SEQ;

    // staging: 512 threads cover 64 rows x 8 chunks once each for K and V
    int srow = tid >> 3, scol = tid & 7;
    const unsigned short* kp = kbase + (size_t)srow * 2304 + scol * 8;
    const unsigned short* vp = vbase + (size_t)srow * SEQ + scol * 8;
    unsigned short* kl = &k_lds[srow * LDK + scol * 8];
    unsigned short* vl = &v_lds[srow * LDK + scol * 8];

    // prefetch tile 0 into registers
    uint4 kr = *reinterpret_cast<const uint4*>(kp);
    uint4 vr = *reinterpret_cast<const uint4*>(vp);

    int prow  = (qq * 32 + ln) * LDK + kh * 32 + hk * 4;   // P write base
    int parow = (qq * 32 + ln) * LDK + kh * 32 + hk * 8;   // P read base

    for (int kt = 0; kt < SEQ; kt += 64) {
        __syncthreads();   // all waves done reading k/v/p of previous tile
        *reinterpret_cast<uint4*>(kl) = kr;
        *reinterpret_cast<uint4*>(vl) = vr;
        __syncthreads();   // staged tile visible
        int ktn = kt + 64;
        if (ktn < SEQ) {   // issue next-tile loads; waited at next iter's ds_write
            kr = *reinterpret_cast<const uint4*>(kp + (size_t)ktn * 2304);
            vr = *reinterpret_cast<const uint4*>(vp + ktn);
        }
        // S^T = K·Q^T over this wave's 32-key half. C: row=key, col=q
        f16v z = {};
        {
            int krow = (kh * 32 + ln) * LDK + hk * 8;
            bf8 a0 = *reinterpret_cast<const bf8*>(&k_lds[krow]);
            bf8 a1 = *reinterpret_cast<const bf8*>(&k_lds[krow + 16]);
            bf8 a2 = *reinterpret_cast<const bf8*>(&k_lds[krow + 32]);
            bf8 a3 = *reinterpret_cast<const bf8*>(&k_lds[krow + 48]);
            z = __builtin_amdgcn_mfma_f32_32x32x16_bf16(a0, qf[0], z, 0, 0, 0);
            z = __builtin_amdgcn_mfma_f32_32x32x16_bf16(a1, qf[1], z, 0, 0, 0);
            z = __builtin_amdgcn_mfma_f32_32x32x16_bf16(a2, qf[2], z, 0, 0, 0);
            z = __builtin_amdgcn_mfma_f32_32x32x16_bf16(a3, qf[3], z, 0, 0, 0);
        }
        // exp2 + pack + wave-private P write: reg 4g+i -> key = 8g + 4*hk + i (+kh*32)
        for (int gg = 0; gg < 4; ++gg) {
            float p0 = exp2f(z[4 * gg]),     p1 = exp2f(z[4 * gg + 1]);
            float p2 = exp2f(z[4 * gg + 2]), p3 = exp2f(z[4 * gg + 3]);
            lsum += (p0 + p1) + (p2 + p3);
            uint2 pk;
            pk.x = pack2bf(p0, p1);
            pk.y = pack2bf(p2, p3);
            *reinterpret_cast<uint2*>(&p_lds[prow + gg * 8]) = pk;
        }
        // O += P·V over this wave's key-half (no barrier: wave-private P rows,
        // DS pipe in-order per wave; v_lds covered by pre-compute barrier)
        bf8 pa0 = *reinterpret_cast<const bf8*>(&p_lds[parow]);
        bf8 pa1 = *reinterpret_cast<const bf8*>(&p_lds[parow + 16]);
        for (int db = 0; db < 2; ++db) {
            int vrow = (db * 32 + ln) * LDK + kh * 32 + hk * 8;
            bf8 v0 = *reinterpret_cast<const bf8*>(&v_lds[vrow]);
            bf8 v1 = *reinterpret_cast<const bf8*>(&v_lds[vrow + 16]);
            acc[db] = __builtin_amdgcn_mfma_f32_32x32x16_bf16(pa0, v0, acc[db], 0, 0, 0);
            acc[db] = __builtin_amdgcn_mfma_f32_32x32x16_bf16(pa1, v1, acc[db], 0, 0, 0);
        }
    }
    // combine the two key-halves (wave pairs w, w^1) through reused LDS
    lsum += __shfl_xor(lsum, 32);   // full key-half sum for q = qq*32+ln
    __syncthreads();                // everyone done with k/v/p before reuse
    float* olds  = reinterpret_cast<float*>(smem);   // 8192 floats = 32768 B
    float* l_lds = olds + 8192;                      // 128 floats
    if (kh) {
        for (int db = 0; db < 2; ++db)
            for (int gg = 0; gg < 4; ++gg) {
                float4 vv = { acc[db][4 * gg], acc[db][4 * gg + 1],
                              acc[db][4 * gg + 2], acc[db][4 * gg + 3] };
                *reinterpret_cast<float4*>(&olds[(qq * 2 + db) * 1024 + gg * 256 + lane * 4]) = vv;
            }
        if (lane < 32) l_lds[qq * 32 + lane] = lsum;
    }
    __syncthreads();
    if (!kh) {
        float linv = 1.0f / (lsum + l_lds[qq * 32 + ln]);
        for (int db = 0; db < 2; ++db)
            for (int gg = 0; gg < 4; ++gg) {
                float4 vv = *reinterpret_cast<float4*>(
                    &olds[(qq * 2 + db) * 1024 + gg * 256 + lane * 4]);
                acc[db][4 * gg]     += vv.x;
                acc[db][4 * gg + 1] += vv.y;
                acc[db][4 * gg + 2] += vv.z;
                acc[db][4 * gg + 3] += vv.w;
            }
        for (int db = 0; db < 2; ++db)
            for (int reg = 0; reg < 16; ++reg) {
                int qrow = (reg & 3) + 8 * (reg >> 2) + 4 * hk;
                float li = __shfl(linv, qrow);   // lane qrow holds q=qq*32+qrow
                int q = q0 + qq * 32 + qrow;
                out[(size_t)(b * SEQ + q) * 768 + h * 64 + db * 32 + ln] =
                    f2bf(acc[db][reg] * li);
            }
    }
}

extern "C" void kernel_launch(void* const* d_in, const int* in_sizes, int n_in,
                              void* d_out, int out_size, void* d_ws, size_t ws_size,
                              hipStream_t stream) {
    const float* x      = (const float*)d_in[0];
    const float* w_qkv  = (const float*)d_in[1];
    const float* b_qkv  = (const float*)d_in[2];
    const float* w_proj = (const float*)d_in[3];
    const float* b_proj = (const float*)d_in[4];
    float* out = (float*)d_out;
    char* ws = (char*)d_ws;
    // workspace layout (bytes); xbf aliases aout (disjoint lifetimes)
    unsigned short* qkv    = (unsigned short*)(ws);                 // 37748736
    unsigned short* vt_buf = (unsigned short*)(ws + 37748736);      // 12582912
    unsigned short* aout   = (unsigned short*)(ws + 50331648);      // 12582912
    unsigned short* xbf    = aout;                                  // alias: dead before attn writes aout
    unsigned short* wqkvT  = (unsigned short*)(ws + 62914560);      // 3538944
    unsigned short* wprojT = (unsigned short*)(ws + 66453504);      // 1179648
    float*          bqkv_s = (float*)(ws + 67633152);               // 9216

    cvt_f32_bf16<<<(M_TOK * EMBED) / 1024, 256, 0, stream>>>(x, xbf, M_TOK * EMBED);
    transpose_f32_bf16<<<dim3(N_QKV / 32, EMBED / 32), dim3(32, 8), 0, stream>>>(
        w_qkv, wqkvT, EMBED, N_QKV, SL2E, 768);
    transpose_f32_bf16<<<dim3(EMBED / 32, EMBED / 32), dim3(32, 8), 0, stream>>>(
        w_proj, wprojT, EMBED, EMBED, 1.0f, 0);
    scale_bias<<<9, 256, 0, stream>>>(b_qkv, bqkv_s);
    gemm_bf16<0><<<dim3(M_TOK / 128, N_QKV / 128), 256, 0, stream>>>(
        xbf, wqkvT, bqkv_s, qkv, M_TOK, N_QKV, EMBED);
    vtrans<<<dim3(SEQ / 64, HEADS, BATCH), 256, 0, stream>>>(qkv, vt_buf);
    attn_kernel<<<768, 512, 0, stream>>>(qkv, vt_buf, aout);
    gemm_bf16<1><<<dim3(M_TOK / 128, EMBED / 128), 256, 0, stream>>>(
        aout, wprojT, b_proj, out, M_TOK, EMBED, EMBED);
}

// Round 8
// 250.048 us; speedup vs baseline: 1.2182x; 1.2182x over previous
//
#include <hip/hip_runtime.h>
#include <hip/hip_bf16.h>

#define EMBED 768
#define HEADS 12
#define HD 64
#define BATCH 4
#define SEQ 2048
#define M_TOK (BATCH*SEQ)   // 8192
#define N_QKV (3*EMBED)     // 2304
#define SL2E 0.18033688011112042f   // (1/8) * log2(e)

typedef short bf8 __attribute__((ext_vector_type(8)));
typedef float f4  __attribute__((ext_vector_type(4)));
typedef float f16v __attribute__((ext_vector_type(16)));
typedef unsigned short us8 __attribute__((ext_vector_type(8)));

static __device__ inline unsigned short f2bf(float f) {
    unsigned int x = __float_as_uint(f);
    unsigned int r = (x + 0x7fffu + ((x >> 16) & 1u)) >> 16;   // RNE
    return (unsigned short)r;
}

// pack two fp32 -> packed bf16x2
static __device__ inline unsigned int pack2bf(float a, float b) {
#if defined(__has_builtin)
#if __has_builtin(__builtin_amdgcn_cvt_pk_bf16_f32)
    auto r = __builtin_amdgcn_cvt_pk_bf16_f32(a, b);
    return __builtin_bit_cast(unsigned int, r);
#else
    unsigned int ua = (__float_as_uint(a) + 0x8000u) >> 16;
    unsigned int ub = (__float_as_uint(b) + 0x8000u) & 0xffff0000u;
    return ua | ub;
#endif
#else
    unsigned int ua = (__float_as_uint(a) + 0x8000u) >> 16;
    unsigned int ub = (__float_as_uint(b) + 0x8000u) & 0xffff0000u;
    return ua | ub;
#endif
}

#define GLD_LDS(gp, lp) __builtin_amdgcn_global_load_lds( \
    (const __attribute__((address_space(1))) void*)(gp),  \
    (__attribute__((address_space(3))) void*)(lp), 16, 0, 0)

// ---------------- fp32 -> bf16 elementwise ----------------
__global__ void cvt_f32_bf16(const float* __restrict__ in,
                             unsigned short* __restrict__ out, int n) {
    int i = (blockIdx.x * blockDim.x + threadIdx.x) * 4;
    if (i < n) {
        float4 v = *reinterpret_cast<const float4*>(in + i);
        ushort4 o;
        o.x = f2bf(v.x); o.y = f2bf(v.y); o.z = f2bf(v.z); o.w = f2bf(v.w);
        *reinterpret_cast<ushort4*>(out + i) = o;
    }
}

// ------- fp32 [R][C] -> bf16 [C][R] transpose; rows<nlim scaled by `scale` -------
__global__ void transpose_f32_bf16(const float* __restrict__ in,
                                   unsigned short* __restrict__ out, int R, int C,
                                   float scale, int nlim) {
    __shared__ float tile[32][33];
    int c0 = blockIdx.x * 32, r0 = blockIdx.y * 32;
    int tx = threadIdx.x, ty = threadIdx.y;      // 32 x 8
    for (int i = 0; i < 32; i += 8)
        tile[ty + i][tx] = in[(size_t)(r0 + ty + i) * C + c0 + tx];
    __syncthreads();
    for (int i = 0; i < 32; i += 8) {
        int orow = c0 + ty + i;
        float s = (orow < nlim) ? scale : 1.0f;
        out[(size_t)orow * R + r0 + tx] = f2bf(tile[tx][ty + i] * s);
    }
}

// ---------------- bias prep: scale first 768 entries by SL2E ----------------
__global__ void scale_bias(const float* __restrict__ in, float* __restrict__ out) {
    int i = blockIdx.x * 256 + threadIdx.x;
    if (i < N_QKV) out[i] = in[i] * (i < 768 ? SL2E : 1.0f);
}

// ---------------- bf16 GEMM: C[M][N] = A[M][K] * BT[N][K]^T + bias ----------------
// m97-pattern staging (unchanged from round 4). Epilogue identical to the proven
// round-1 code — round-2's branchy epilogue demoted acc to scratch (VGPR 28).
template<int OUT_MODE>  // 0: bf16 out, 1: fp32 out
__global__ __launch_bounds__(256) void gemm_bf16(
    const unsigned short* __restrict__ A,
    const unsigned short* __restrict__ BT,
    const float* __restrict__ bias,
    void* __restrict__ Cout, int M, int N, int K)
{
    const int LDA = 32;  // unpadded: lane-linear global_load_lds dest
    __shared__ unsigned short a_lds[128 * 32];
    __shared__ unsigned short b_lds[128 * 32];
    int tid  = threadIdx.x;
    int lane = tid & 63, w = tid >> 6;
    int quad = lane >> 4, cc = lane & 15;
    int m0 = blockIdx.x * 128, n0 = blockIdx.y * 128;
    int wr = w >> 1, wc = w & 1;
    int mb = wr * 64, nb = wc * 64;
    const unsigned short* Ab = A + (size_t)m0 * K;
    const unsigned short* Bb = BT + (size_t)n0 * K;
    f4 acc[4][4] = {};
    for (int k0 = 0; k0 < K; k0 += 32) {
        __syncthreads();
        for (int p = 0; p < 2; ++p) {
            int li  = p * 256 + tid;          // 0..511
            int row = li >> 2, ch = li & 3;   // 128 rows x 4 chunks of 8 halfwords
            GLD_LDS(Ab + (size_t)row * K + k0 + ch * 8, &a_lds[li * 8]);
            GLD_LDS(Bb + (size_t)row * K + k0 + ch * 8, &b_lds[li * 8]);
        }
        __syncthreads();   // vmcnt(0) drain
        bf8 af[4], bfv[4];
        for (int mi = 0; mi < 4; ++mi)
            af[mi] = *reinterpret_cast<const bf8*>(&a_lds[(mb + mi * 16 + cc) * LDA + quad * 8]);
        for (int ni = 0; ni < 4; ++ni)
            bfv[ni] = *reinterpret_cast<const bf8*>(&b_lds[(nb + ni * 16 + cc) * LDA + quad * 8]);
        for (int mi = 0; mi < 4; ++mi)
            for (int ni = 0; ni < 4; ++ni)
                acc[mi][ni] = __builtin_amdgcn_mfma_f32_16x16x32_bf16(af[mi], bfv[ni], acc[mi][ni], 0, 0, 0);
    }
    for (int mi = 0; mi < 4; ++mi)
        for (int ni = 0; ni < 4; ++ni) {
            int gn = n0 + nb + ni * 16 + cc;
            float bv = bias[gn];
            for (int r = 0; r < 4; ++r) {
                int gm = m0 + mb + mi * 16 + quad * 4 + r;
                float v = acc[mi][ni][r] + bv;
                if (OUT_MODE == 0)
                    ((unsigned short*)Cout)[(size_t)gm * N + gn] = f2bf(v);
                else
                    ((float*)Cout)[(size_t)gm * N + gn] = v;
            }
        }
}

// ------- V transpose: qkv[.][1536+h*64+d] -> vt[b][h][d][t], LDS-tiled -------
__global__ __launch_bounds__(256) void vtrans(
    const unsigned short* __restrict__ qkv, unsigned short* __restrict__ vt)
{
    __shared__ unsigned short lds[64 * 72];
    int tid = threadIdx.x;
    int t0 = blockIdx.x * 64, h = blockIdx.y, b = blockIdx.z;
    for (int p = 0; p < 2; ++p) {
        int li = p * 256 + tid, row = li >> 3, col = li & 7;
        *reinterpret_cast<uint4*>(&lds[row * 72 + col * 8]) =
            *reinterpret_cast<const uint4*>(
                qkv + (size_t)(b * SEQ + t0 + row) * 2304 + 1536 + h * 64 + col * 8);
    }
    __syncthreads();
    for (int p = 0; p < 2; ++p) {
        int li = p * 256 + tid, d = li >> 3, tc = li & 7;
        us8 v;
        for (int j = 0; j < 8; ++j) v[j] = lds[(tc * 8 + j) * 72 + d];
        *reinterpret_cast<us8*>(
            vt + ((size_t)(b * HEADS + h) * 64 + d) * SEQ + t0 + tc * 8) = v;
    }
}

// ---------------- flash attention, 32x32x16 MFMA, q x key wave split ----------------
// Round-7 post-mortem: the kernel needs ~100 unified VGPR+AGPR regs/thread;
// __launch_bounds__(512,6) capped it at ~85 -> compiler spilled the accumulators
// (VGPR 40, +75 MB scratch traffic, 158us). (512,4) gives a 128-reg budget:
// no spills, 2 blocks/CU (16 waves). LDS diet from r7 kept: per block-iter
// ~1344 LDS-cyc vs r6's ~2112, conflicts 3.1e6 vs 1.7e7.
__global__ __launch_bounds__(512, 4) void attn_kernel(
    const unsigned short* __restrict__ qkv,  // [B*T][2304] bf16 (q pre-scaled)
    const unsigned short* __restrict__ vt,   // [B][H][64][T] bf16
    unsigned short* __restrict__ out)        // [B*T][768] bf16
{
    const int LDK = 72;  // 64 + 8 pad
    __shared__ unsigned short smem[18432];   // 36864 B total
    unsigned short* k_lds = smem;            // [64][72]
    unsigned short* v_lds = smem + 4608;     // [64][72]
    unsigned short* p_lds = smem + 9216;     // [128][72]
    int tid  = threadIdx.x;
    int lane = tid & 63, w = tid >> 6;       // w = 0..7
    int ln   = lane & 31, hk = lane >> 5;    // n-index / k-half within frag
    int qq   = w >> 1, kh = w & 1;           // q-quarter, key-half
    // swizzle: all 16 q-tiles of one (b,h) share id%8 -> same XCD L2
    int id  = blockIdx.x;
    int sub = id >> 3, rem = id & 7;
    int g   = (sub >> 4) * 8 + rem;          // 0..47
    int qt  = sub & 15;
    int b   = g / HEADS, h = g % HEADS;
    int q0  = qt * 128;

    // Q resident as 32x32 B-fragments: B[n=ln -> q][k=kb*16+hk*8+j]
    bf8 qf[4];
    {
        const unsigned short* qp =
            qkv + (size_t)(b * SEQ + q0 + qq * 32 + ln) * 2304 + h * 64 + hk * 8;
        qf[0] = *reinterpret_cast<const bf8*>(qp);
        qf[1] = *reinterpret_cast<const bf8*>(qp + 16);
        qf[2] = *reinterpret_cast<const bf8*>(qp + 32);
        qf[3] = *reinterpret_cast<const bf8*>(qp + 48);
    }
    f16v acc[2] = {};            // [db=d/32]; C: col d = db*32+ln, row q = (reg&3)+8*(reg>>2)+4*hk
    float lsum = 0.f;
    const unsigned short* kbase = qkv + (size_t)b * SEQ * 2304 + 768 + h * 64;
    const unsigned short* vbase = vt + (size_t)(b * HEADS + h) * 64 * SEQ;

    // staging: 512 threads cover 64 rows x 8 chunks once each for K and V
    int srow = tid >> 3, scol = tid & 7;
    const unsigned short* kp = kbase + (size_t)srow * 2304 + scol * 8;
    const unsigned short* vp = vbase + (size_t)srow * SEQ + scol * 8;
    unsigned short* kl = &k_lds[srow * LDK + scol * 8];
    unsigned short* vl = &v_lds[srow * LDK + scol * 8];

    // prefetch tile 0 into registers
    uint4 kr = *reinterpret_cast<const uint4*>(kp);
    uint4 vr = *reinterpret_cast<const uint4*>(vp);

    int prow  = (qq * 32 + ln) * LDK + kh * 32 + hk * 4;   // P write base
    int parow = (qq * 32 + ln) * LDK + kh * 32 + hk * 8;   // P read base

    for (int kt = 0; kt < SEQ; kt += 64) {
        __syncthreads();   // all waves done reading k/v/p of previous tile
        *reinterpret_cast<uint4*>(kl) = kr;
        *reinterpret_cast<uint4*>(vl) = vr;
        __syncthreads();   // staged tile visible
        int ktn = kt + 64;
        if (ktn < SEQ) {   // issue next-tile loads; waited at next iter's ds_write
            kr = *reinterpret_cast<const uint4*>(kp + (size_t)ktn * 2304);
            vr = *reinterpret_cast<const uint4*>(vp + ktn);
        }
        // S^T = K·Q^T over this wave's 32-key half. C: row=key, col=q
        f16v z = {};
        {
            int krow = (kh * 32 + ln) * LDK + hk * 8;
            bf8 a0 = *reinterpret_cast<const bf8*>(&k_lds[krow]);
            bf8 a1 = *reinterpret_cast<const bf8*>(&k_lds[krow + 16]);
            bf8 a2 = *reinterpret_cast<const bf8*>(&k_lds[krow + 32]);
            bf8 a3 = *reinterpret_cast<const bf8*>(&k_lds[krow + 48]);
            z = __builtin_amdgcn_mfma_f32_32x32x16_bf16(a0, qf[0], z, 0, 0, 0);
            z = __builtin_amdgcn_mfma_f32_32x32x16_bf16(a1, qf[1], z, 0, 0, 0);
            z = __builtin_amdgcn_mfma_f32_32x32x16_bf16(a2, qf[2], z, 0, 0, 0);
            z = __builtin_amdgcn_mfma_f32_32x32x16_bf16(a3, qf[3], z, 0, 0, 0);
        }
        // exp2 + pack + wave-private P write: reg 4g+i -> key = 8g + 4*hk + i (+kh*32)
        for (int gg = 0; gg < 4; ++gg) {
            float p0 = exp2f(z[4 * gg]),     p1 = exp2f(z[4 * gg + 1]);
            float p2 = exp2f(z[4 * gg + 2]), p3 = exp2f(z[4 * gg + 3]);
            lsum += (p0 + p1) + (p2 + p3);
            uint2 pk;
            pk.x = pack2bf(p0, p1);
            pk.y = pack2bf(p2, p3);
            *reinterpret_cast<uint2*>(&p_lds[prow + gg * 8]) = pk;
        }
        // O += P·V over this wave's key-half (no barrier: wave-private P rows,
        // DS pipe in-order per wave; v_lds covered by pre-compute barrier)
        bf8 pa0 = *reinterpret_cast<const bf8*>(&p_lds[parow]);
        bf8 pa1 = *reinterpret_cast<const bf8*>(&p_lds[parow + 16]);
        for (int db = 0; db < 2; ++db) {
            int vrow = (db * 32 + ln) * LDK + kh * 32 + hk * 8;
            bf8 v0 = *reinterpret_cast<const bf8*>(&v_lds[vrow]);
            bf8 v1 = *reinterpret_cast<const bf8*>(&v_lds[vrow + 16]);
            acc[db] = __builtin_amdgcn_mfma_f32_32x32x16_bf16(pa0, v0, acc[db], 0, 0, 0);
            acc[db] = __builtin_amdgcn_mfma_f32_32x32x16_bf16(pa1, v1, acc[db], 0, 0, 0);
        }
    }
    // combine the two key-halves (wave pairs w, w^1) through reused LDS
    lsum += __shfl_xor(lsum, 32);   // full key-half sum for q = qq*32+ln
    __syncthreads();                // everyone done with k/v/p before reuse
    float* olds  = reinterpret_cast<float*>(smem);   // 8192 floats = 32768 B
    float* l_lds = olds + 8192;                      // 128 floats
    if (kh) {
        for (int db = 0; db < 2; ++db)
            for (int gg = 0; gg < 4; ++gg) {
                float4 vv = { acc[db][4 * gg], acc[db][4 * gg + 1],
                              acc[db][4 * gg + 2], acc[db][4 * gg + 3] };
                *reinterpret_cast<float4*>(&olds[(qq * 2 + db) * 1024 + gg * 256 + lane * 4]) = vv;
            }
        if (lane < 32) l_lds[qq * 32 + lane] = lsum;
    }
    __syncthreads();
    if (!kh) {
        float linv = 1.0f / (lsum + l_lds[qq * 32 + ln]);
        for (int db = 0; db < 2; ++db)
            for (int gg = 0; gg < 4; ++gg) {
                float4 vv = *reinterpret_cast<float4*>(
                    &olds[(qq * 2 + db) * 1024 + gg * 256 + lane * 4]);
                acc[db][4 * gg]     += vv.x;
                acc[db][4 * gg + 1] += vv.y;
                acc[db][4 * gg + 2] += vv.z;
                acc[db][4 * gg + 3] += vv.w;
            }
        for (int db = 0; db < 2; ++db)
            for (int reg = 0; reg < 16; ++reg) {
                int qrow = (reg & 3) + 8 * (reg >> 2) + 4 * hk;
                float li = __shfl(linv, qrow);   // lane qrow holds q=qq*32+qrow
                int q = q0 + qq * 32 + qrow;
                out[(size_t)(b * SEQ + q) * 768 + h * 64 + db * 32 + ln] =
                    f2bf(acc[db][reg] * li);
            }
    }
}

extern "C" void kernel_launch(void* const* d_in, const int* in_sizes, int n_in,
                              void* d_out, int out_size, void* d_ws, size_t ws_size,
                              hipStream_t stream) {
    const float* x      = (const float*)d_in[0];
    const float* w_qkv  = (const float*)d_in[1];
    const float* b_qkv  = (const float*)d_in[2];
    const float* w_proj = (const float*)d_in[3];
    const float* b_proj = (const float*)d_in[4];
    float* out = (float*)d_out;
    char* ws = (char*)d_ws;
    // workspace layout (bytes); xbf aliases aout (disjoint lifetimes)
    unsigned short* qkv    = (unsigned short*)(ws);                 // 37748736
    unsigned short* vt_buf = (unsigned short*)(ws + 37748736);      // 12582912
    unsigned short* aout   = (unsigned short*)(ws + 50331648);      // 12582912
    unsigned short* xbf    = aout;                                  // alias: dead before attn writes aout
    unsigned short* wqkvT  = (unsigned short*)(ws + 62914560);      // 3538944
    unsigned short* wprojT = (unsigned short*)(ws + 66453504);      // 1179648
    float*          bqkv_s = (float*)(ws + 67633152);               // 9216

    cvt_f32_bf16<<<(M_TOK * EMBED) / 1024, 256, 0, stream>>>(x, xbf, M_TOK * EMBED);
    transpose_f32_bf16<<<dim3(N_QKV / 32, EMBED / 32), dim3(32, 8), 0, stream>>>(
        w_qkv, wqkvT, EMBED, N_QKV, SL2E, 768);
    transpose_f32_bf16<<<dim3(EMBED / 32, EMBED / 32), dim3(32, 8), 0, stream>>>(
        w_proj, wprojT, EMBED, EMBED, 1.0f, 0);
    scale_bias<<<9, 256, 0, stream>>>(b_qkv, bqkv_s);
    gemm_bf16<0><<<dim3(M_TOK / 128, N_QKV / 128), 256, 0, stream>>>(
        xbf, wqkvT, bqkv_s, qkv, M_TOK, N_QKV, EMBED);
    vtrans<<<dim3(SEQ / 64, HEADS, BATCH), 256, 0, stream>>>(qkv, vt_buf);
    attn_kernel<<<768, 512, 0, stream>>>(qkv, vt_buf, aout);
    gemm_bf16<1><<<dim3(M_TOK / 128, EMBED / 128), 256, 0, stream>>>(
        aout, wprojT, b_proj, out, M_TOK, EMBED, EMBED);
}